// Round 1
// baseline (50.680 us; speedup 1.0000x reference)
//
#include <hip/hip_runtime.h>
#include <math.h>

#define EPS 1e-6f
#define BN_EPSF 1e-5f
#define PI2F 6.2831853071795864769f
#define NBB 4
#define NCC 512
#define NGG 2048
#define CHN 3
#define NPAR 3
#define OUTC 64
#define NBAS 10

// d_out layout (floats): y_out, n_f, fourier_prior, n_h1, h0_f
#define Y_OFF   0
#define NF_OFF  (NBB*NGG*OUTC)                 // 524288
#define FP_OFF  (NF_OFF  + NBB*NGG*CHN*NPAR)  // 598016
#define NH1_OFF (FP_OFF  + NBB*NGG*CHN*NPAR)  // 671744
#define H0_OFF  (NH1_OFF + NBB*NGG*CHN*NPAR)  // 745472

// ws layout (floats)
#define WS_PRE   0
#define WS_CONV  (NBB*CHN*NPAR*NGG)           // 73728
#define WS_STATS (2*NBB*CHN*NPAR*NGG)         // 147456 (18 floats: sum[9], sumsq[9])

__global__ __launch_bounds__(256) void k1_rbf(
    const float* __restrict__ x_c, const float* __restrict__ y_c,
    const float* __restrict__ x_g, const float* __restrict__ sigma,
    const float* __restrict__ mu, const float* __restrict__ eps1,
    const float* __restrict__ b_u, const float* __restrict__ random_w,
    float* __restrict__ out, float* __restrict__ ws)
{
    const int bid = blockIdx.x;
    const int b = bid >> 6;        // 64 g-tiles per batch
    const int gtile = bid & 63;
    const int tid = threadIdx.x;

    __shared__ float4 cxy[NCC][2];          // (xc0,yc0,xc1,yc1),(xc2,yc2,-,-)
    __shared__ float red[8][32][18];        // [chunk][g_local][h0(9),h1(9)]
    __shared__ float sw_l[NBAS*NPAR], sb_l[NBAS*NPAR], rw_l[NBAS];

    // stage context set for this batch
    const float* xcb = x_c + b*NCC*CHN;
    const float* ycb = y_c + b*NCC*CHN;
    float* cf = (float*)cxy;
    for (int i = tid; i < NCC*CHN; i += 256) {
        int n = i / 3, c = i - n*3;
        cf[n*8 + 2*c]     = xcb[i];
        cf[n*8 + 2*c + 1] = ycb[i];
    }
    if (tid < NBAS*NPAR) {
        int k = tid / 3, p = tid - k*3;
        float wmu  = expf(mu[p]);
        float wstd = 1.0f / (expf(sigma[p]) + EPS);
        sw_l[tid] = wmu + wstd * eps1[(b*NBAS + k)*NPAR + p];
        sb_l[tid] = PI2F * b_u[(b*NBAS + k)*NPAR + p];
    }
    if (tid < NBAS) rw_l[tid] = random_w[tid];

    const int g_local = tid & 31;
    const int chunk   = tid >> 5;           // 8 chunks of 64 context points
    const int g = gtile*32 + g_local;
    const float xg0 = x_g[(b*NGG + g)*3 + 0];
    const float xg1 = x_g[(b*NGG + g)*3 + 1];
    const float xg2 = x_g[(b*NGG + g)*3 + 2];
    float coef[3];
    #pragma unroll
    for (int p = 0; p < 3; ++p) {
        float s = expf(sigma[p]) + EPS;
        coef[p] = -0.5f / (s*s);
    }

    __syncthreads();

    float h0a[3][3] = {{0}}, h1a[3][3] = {{0}};
    const int n0 = chunk*64;
    for (int n = n0; n < n0 + 64; ++n) {
        float4 A = cxy[n][0];
        float4 B = cxy[n][1];
        float d0 = A.x - xg0, d1 = A.z - xg1, d2 = B.x - xg2;
        float dx2[3] = {d0*d0, d1*d1, d2*d2};
        float yv[3]  = {A.y, A.w, B.y};
        #pragma unroll
        for (int c = 0; c < 3; ++c) {
            #pragma unroll
            for (int p = 0; p < 3; ++p) {
                float w = expf(dx2[c] * coef[p]);
                h0a[c][p] += w;
                h1a[c][p] += w * yv[c];
            }
        }
    }
    #pragma unroll
    for (int c = 0; c < 3; ++c)
        #pragma unroll
        for (int p = 0; p < 3; ++p) {
            red[chunk][g_local][c*3 + p]     = h0a[c][p];
            red[chunk][g_local][9 + c*3 + p] = h1a[c][p];
        }
    __syncthreads();

    // finalize 32*9 = 288 outputs
    for (int it = tid; it < 32*9; it += 256) {
        int gl = it / 9, cp = it - gl*9;
        int c = cp / 3, p = cp - c*3;
        float h0 = 0.f, h1 = 0.f;
        #pragma unroll
        for (int q = 0; q < 8; ++q) {
            h0 += red[q][gl][cp];
            h1 += red[q][gl][9 + cp];
        }
        int gg = gtile*32 + gl;
        float nh1 = h1 / (h0 + EPS);
        float xg = x_g[(b*NGG + gg)*3 + c];
        float fp = 0.f;
        #pragma unroll
        for (int k = 0; k < NBAS; ++k) {
            // match numpy rounding: separate mul + add (no fma contraction)
            float arg = __fadd_rn(__fmul_rn(sw_l[k*3 + p], xg), sb_l[k*3 + p]);
            fp += rw_l[k] * cosf(arg);
        }
        fp *= 0.44721359549995793f;  // sqrt(2/10)
        int base = (b*NGG + gg)*9 + cp;
        out[H0_OFF  + base] = h0;
        out[NH1_OFF + base] = nh1;
        out[FP_OFF  + base] = fp;
        ws[WS_PRE + (b*9 + cp)*NGG + gg] = nh1 + fp;
    }
}

__global__ __launch_bounds__(256) void k2_conv(
    const float* __restrict__ cw1, const float* __restrict__ cb1,
    const float* __restrict__ cw2, const float* __restrict__ cb2,
    const float* __restrict__ cw3, const float* __restrict__ cb3,
    float* __restrict__ ws)
{
    int bid = blockIdx.x;                 // nb*9*8 = 288
    int b = bid / 72; int r = bid - b*72;
    int cp = r / 8;  int gc = r - cp*8;
    int g = gc*256 + threadIdx.x;
    int c = cp / 3, p = cp - c*3;
    const float* pre = ws + WS_PRE + (b*9 + cp)*NGG;

    int K, pad; const float* w; float bias;
    if (p == 0)      { K = 3; pad = 1; w = cw1 + c*3; bias = cb1[c]; }
    else if (p == 1) { K = 5; pad = 2; w = cw2 + c*5; bias = cb2[c]; }
    else             { K = 9; pad = 4; w = cw3 + c*9; bias = cb3[c]; }

    float acc = bias;
    for (int k = 0; k < K; ++k) {
        int idx = g - pad + k;
        if (idx >= 0 && idx < NGG) acc += w[k] * pre[idx];
    }
    ws[WS_CONV + (b*9 + cp)*NGG + g] = acc;

    // BN stats: block reduce then one atomic per block
    float s1 = acc, s2 = acc*acc;
    #pragma unroll
    for (int o = 32; o > 0; o >>= 1) {
        s1 += __shfl_down(s1, o);
        s2 += __shfl_down(s2, o);
    }
    __shared__ float r1[4], r2[4];
    int lane = threadIdx.x & 63, wv = threadIdx.x >> 6;
    if (lane == 0) { r1[wv] = s1; r2[wv] = s2; }
    __syncthreads();
    if (threadIdx.x == 0) {
        float t1 = r1[0] + r1[1] + r1[2] + r1[3];
        float t2 = r2[0] + r2[1] + r2[2] + r2[3];
        atomicAdd(&ws[WS_STATS + cp], t1);
        atomicAdd(&ws[WS_STATS + 9 + cp], t2);
    }
}

__global__ __launch_bounds__(256) void k3_out(
    const float* __restrict__ bn_gamma, const float* __restrict__ bn_beta,
    const float* __restrict__ g_w, const float* __restrict__ g_b,
    float* __restrict__ out, float* __restrict__ ws)
{
    __shared__ float gw_l[OUTC*18];
    __shared__ float feat_l[4][18];
    const int tid = threadIdx.x;
    for (int i = tid; i < OUTC*18; i += 256) gw_l[i] = g_w[i];

    if (tid < 72) {
        int pt = tid / 18, j = tid - pt*18;
        int P = blockIdx.x*4 + pt;
        int b = P >> 11, g = P & 2047;
        float f;
        if (j < 9) {
            f = out[H0_OFF + (b*NGG + g)*9 + j];
        } else {
            int cp = j - 9; int c = cp / 3, p = cp - c*3;
            float s1 = ws[WS_STATS + cp], s2 = ws[WS_STATS + 9 + cp];
            float mean = s1 * (1.0f/8192.0f);
            float var  = s2 * (1.0f/8192.0f) - mean*mean;
            float iv = rsqrtf(var + BN_EPSF);
            float x = ws[WS_CONV + (b*9 + cp)*NGG + g];
            float v = bn_gamma[p*3 + c] * (x - mean) * iv + bn_beta[p*3 + c];
            out[NF_OFF + (b*NGG + g)*9 + cp] = v;
            f = v;
        }
        feat_l[pt][j] = f;
    }
    __syncthreads();

    int pt = tid >> 6, o = tid & 63;
    int P = blockIdx.x*4 + pt;
    int b = P >> 11, g = P & 2047;
    float acc = g_b[o];
    #pragma unroll
    for (int j = 0; j < 18; ++j) acc += feat_l[pt][j] * gw_l[o*18 + j];
    out[Y_OFF + (b*NGG + g)*OUTC + o] = acc;
}

extern "C" void kernel_launch(void* const* d_in, const int* in_sizes, int n_in,
                              void* d_out, int out_size, void* d_ws, size_t ws_size,
                              hipStream_t stream)
{
    const float* x_c      = (const float*)d_in[0];
    const float* y_c      = (const float*)d_in[1];
    const float* x_g      = (const float*)d_in[2];
    const float* sigma    = (const float*)d_in[3];
    const float* mu       = (const float*)d_in[4];
    const float* eps1     = (const float*)d_in[5];
    const float* b_u      = (const float*)d_in[6];
    const float* random_w = (const float*)d_in[7];
    const float* conv_w1  = (const float*)d_in[8];
    const float* conv_b1  = (const float*)d_in[9];
    const float* conv_w2  = (const float*)d_in[10];
    const float* conv_b2  = (const float*)d_in[11];
    const float* conv_w3  = (const float*)d_in[12];
    const float* conv_b3  = (const float*)d_in[13];
    const float* bn_gamma = (const float*)d_in[14];
    const float* bn_beta  = (const float*)d_in[15];
    const float* g_w      = (const float*)d_in[16];
    const float* g_b      = (const float*)d_in[17];

    float* outp = (float*)d_out;
    float* wsp  = (float*)d_ws;

    // zero the BN-stats accumulators (ws is poisoned, and we atomicAdd into it)
    hipMemsetAsync((void*)(wsp + WS_STATS), 0, 18*sizeof(float), stream);

    k1_rbf<<<NBB*(NGG/32), 256, 0, stream>>>(x_c, y_c, x_g, sigma, mu, eps1, b_u,
                                             random_w, outp, wsp);
    k2_conv<<<NBB*9*(NGG/256), 256, 0, stream>>>(conv_w1, conv_b1, conv_w2, conv_b2,
                                                 conv_w3, conv_b3, wsp);
    k3_out<<<(NBB*NGG)/4, 256, 0, stream>>>(bn_gamma, bn_beta, g_w, g_b, outp, wsp);
}

// Round 2
// 28.667 us; speedup vs baseline: 1.7679x; 1.7679x over previous
//
#include <hip/hip_runtime.h>
#include <math.h>

#define EPS 1e-6f
#define BN_EPSF 1e-5f
#define PI2F 6.2831853071795864769f
#define LOG2EF 1.4426950408889634f
#define NBB 4
#define NCC 512
#define NGG 2048
#define CHN 3
#define NPAR 3
#define OUTC 64
#define NBAS 10

// d_out layout (floats): y_out, n_f, fourier_prior, n_h1, h0_f
#define Y_OFF   0
#define NF_OFF  (NBB*NGG*OUTC)                 // 524288
#define FP_OFF  (NF_OFF  + NBB*NGG*CHN*NPAR)  // 598016
#define NH1_OFF (FP_OFF  + NBB*NGG*CHN*NPAR)  // 671744
#define H0_OFF  (NH1_OFF + NBB*NGG*CHN*NPAR)  // 745472

// ws layout (floats)
#define WS_PRE   0
#define WS_CONV  (NBB*CHN*NPAR*NGG)           // 73728
#define WS_STATS (2*NBB*CHN*NPAR*NGG)         // 147456: 9 cps * 32 blocks * {sum,sumsq}

#if defined(__has_builtin)
# if __has_builtin(__builtin_amdgcn_exp2f)
#  define EXP2F(x) __builtin_amdgcn_exp2f(x)
# endif
#endif
#ifndef EXP2F
# define EXP2F(x) exp2f(x)
#endif

__global__ __launch_bounds__(256) void k1_rbf(
    const float* __restrict__ x_c, const float* __restrict__ y_c,
    const float* __restrict__ x_g, const float* __restrict__ sigma,
    const float* __restrict__ mu, const float* __restrict__ eps1,
    const float* __restrict__ b_u, const float* __restrict__ random_w,
    float* __restrict__ out, float* __restrict__ ws)
{
    const int bid = blockIdx.x;
    const int b = bid >> 6;        // 64 g-tiles per batch
    const int gtile = bid & 63;
    const int tid = threadIdx.x;

    __shared__ float4 cxy[NCC][2];          // (xc0,yc0,xc1,yc1),(xc2,yc2,-,-)
    __shared__ float red[8][32][18];        // [chunk][g_local][h0(9),h1(9)]
    __shared__ float sw_l[NBAS*NPAR], sb_l[NBAS*NPAR], rw_l[NBAS];

    // stage context set for this batch
    const float* xcb = x_c + b*NCC*CHN;
    const float* ycb = y_c + b*NCC*CHN;
    float* cf = (float*)cxy;
    for (int i = tid; i < NCC*CHN; i += 256) {
        int n = i / 3, c = i - n*3;
        cf[n*8 + 2*c]     = xcb[i];
        cf[n*8 + 2*c + 1] = ycb[i];
    }
    if (tid < NBAS*NPAR) {
        int k = tid / 3, p = tid - k*3;
        float wmu  = expf(mu[p]);
        float wstd = 1.0f / (expf(sigma[p]) + EPS);
        sw_l[tid] = wmu + wstd * eps1[(b*NBAS + k)*NPAR + p];
        sb_l[tid] = PI2F * b_u[(b*NBAS + k)*NPAR + p];
    }
    if (tid < NBAS) rw_l[tid] = random_w[tid];

    const int g_local = tid & 31;
    const int chunk   = tid >> 5;           // 8 chunks of 64 context points
    const int g = gtile*32 + g_local;
    const float xg0 = x_g[(b*NGG + g)*3 + 0];
    const float xg1 = x_g[(b*NGG + g)*3 + 1];
    const float xg2 = x_g[(b*NGG + g)*3 + 2];
    float coef[3];
    #pragma unroll
    for (int p = 0; p < 3; ++p) {
        float s = expf(sigma[p]) + EPS;
        coef[p] = (-0.5f * LOG2EF) / (s*s);   // exp(-0.5 d^2) == exp2(d^2 * coef)
    }

    __syncthreads();

    float h0a[3][3] = {{0}}, h1a[3][3] = {{0}};
    const int n0 = chunk*64;
    for (int n = n0; n < n0 + 64; ++n) {
        float4 A = cxy[n][0];
        float4 B = cxy[n][1];
        float d0 = A.x - xg0, d1 = A.z - xg1, d2 = B.x - xg2;
        float dx2[3] = {d0*d0, d1*d1, d2*d2};
        float yv[3]  = {A.y, A.w, B.y};
        #pragma unroll
        for (int c = 0; c < 3; ++c) {
            #pragma unroll
            for (int p = 0; p < 3; ++p) {
                float w = EXP2F(dx2[c] * coef[p]);   // one v_mul + one v_exp_f32
                h0a[c][p] += w;
                h1a[c][p] += w * yv[c];
            }
        }
    }
    #pragma unroll
    for (int c = 0; c < 3; ++c)
        #pragma unroll
        for (int p = 0; p < 3; ++p) {
            red[chunk][g_local][c*3 + p]     = h0a[c][p];
            red[chunk][g_local][9 + c*3 + p] = h1a[c][p];
        }
    __syncthreads();

    // finalize 32*9 = 288 outputs
    for (int it = tid; it < 32*9; it += 256) {
        int gl = it / 9, cp = it - gl*9;
        int c = cp / 3, p = cp - c*3;
        float h0 = 0.f, h1 = 0.f;
        #pragma unroll
        for (int q = 0; q < 8; ++q) {
            h0 += red[q][gl][cp];
            h1 += red[q][gl][9 + cp];
        }
        int gg = gtile*32 + gl;
        float nh1 = h1 / (h0 + EPS);
        float xg = x_g[(b*NGG + gg)*3 + c];
        float fp = 0.f;
        #pragma unroll
        for (int k = 0; k < NBAS; ++k) {
            // match numpy rounding: separate mul + add (no fma contraction)
            float arg = __fadd_rn(__fmul_rn(sw_l[k*3 + p], xg), sb_l[k*3 + p]);
            fp += rw_l[k] * cosf(arg);   // args reach ~4e4: must keep accurate cosf
        }
        fp *= 0.44721359549995793f;  // sqrt(2/10)
        int base = (b*NGG + gg)*9 + cp;
        out[H0_OFF  + base] = h0;
        out[NH1_OFF + base] = nh1;
        out[FP_OFF  + base] = fp;
        ws[WS_PRE + (b*9 + cp)*NGG + gg] = nh1 + fp;
    }
}

__global__ __launch_bounds__(256) void k2_conv(
    const float* __restrict__ cw1, const float* __restrict__ cb1,
    const float* __restrict__ cw2, const float* __restrict__ cb2,
    const float* __restrict__ cw3, const float* __restrict__ cb3,
    float* __restrict__ ws)
{
    int bid = blockIdx.x;                 // nb*9*8 = 288
    int b = bid / 72; int r = bid - b*72;
    int cp = r / 8;  int gc = r - cp*8;
    int g = gc*256 + threadIdx.x;
    int c = cp / 3, p = cp - c*3;
    const float* pre = ws + WS_PRE + (b*9 + cp)*NGG;

    int K, pad; const float* w; float bias;
    if (p == 0)      { K = 3; pad = 1; w = cw1 + c*3; bias = cb1[c]; }
    else if (p == 1) { K = 5; pad = 2; w = cw2 + c*5; bias = cb2[c]; }
    else             { K = 9; pad = 4; w = cw3 + c*9; bias = cb3[c]; }

    float acc = bias;
    for (int k = 0; k < K; ++k) {
        int idx = g - pad + k;
        if (idx >= 0 && idx < NGG) acc += w[k] * pre[idx];
    }
    ws[WS_CONV + (b*9 + cp)*NGG + g] = acc;

    // BN stats: block reduce, then DETERMINISTIC per-block partial (no atomics,
    // no pre-zeroing needed -> no memset dispatch in the graph)
    float s1 = acc, s2 = acc*acc;
    #pragma unroll
    for (int o = 32; o > 0; o >>= 1) {
        s1 += __shfl_down(s1, o);
        s2 += __shfl_down(s2, o);
    }
    __shared__ float r1[4], r2[4];
    int lane = threadIdx.x & 63, wv = threadIdx.x >> 6;
    if (lane == 0) { r1[wv] = s1; r2[wv] = s2; }
    __syncthreads();
    if (threadIdx.x == 0) {
        float t1 = r1[0] + r1[1] + r1[2] + r1[3];
        float t2 = r2[0] + r2[1] + r2[2] + r2[3];
        int pidx = cp*32 + b*8 + gc;
        ws[WS_STATS + pidx*2]     = t1;
        ws[WS_STATS + pidx*2 + 1] = t2;
    }
}

__global__ __launch_bounds__(256) void k3_out(
    const float* __restrict__ bn_gamma, const float* __restrict__ bn_beta,
    const float* __restrict__ g_w, const float* __restrict__ g_b,
    float* __restrict__ out, float* __restrict__ ws)
{
    __shared__ float gw_l[OUTC*18];
    __shared__ float feat_l[4][18];
    const int tid = threadIdx.x;
    for (int i = tid; i < OUTC*18; i += 256) gw_l[i] = g_w[i];

    if (tid < 72) {
        int pt = tid / 18, j = tid - pt*18;
        int P = blockIdx.x*4 + pt;
        int b = P >> 11, g = P & 2047;
        float f;
        if (j < 9) {
            f = out[H0_OFF + (b*NGG + g)*9 + j];
        } else {
            int cp = j - 9; int c = cp / 3, p = cp - c*3;
            float s1 = 0.f, s2 = 0.f;
            #pragma unroll 8
            for (int q = 0; q < 32; ++q) {
                s1 += ws[WS_STATS + (cp*32 + q)*2];
                s2 += ws[WS_STATS + (cp*32 + q)*2 + 1];
            }
            float mean = s1 * (1.0f/8192.0f);
            float var  = s2 * (1.0f/8192.0f) - mean*mean;
            float iv = rsqrtf(var + BN_EPSF);
            float x = ws[WS_CONV + (b*9 + cp)*NGG + g];
            float v = bn_gamma[p*3 + c] * (x - mean) * iv + bn_beta[p*3 + c];
            out[NF_OFF + (b*NGG + g)*9 + cp] = v;
            f = v;
        }
        feat_l[pt][j] = f;
    }
    __syncthreads();

    int pt = tid >> 6, o = tid & 63;
    int P = blockIdx.x*4 + pt;
    int b = P >> 11, g = P & 2047;
    float acc = g_b[o];
    #pragma unroll
    for (int j = 0; j < 18; ++j) acc += feat_l[pt][j] * gw_l[o*18 + j];
    out[Y_OFF + (b*NGG + g)*OUTC + o] = acc;
}

extern "C" void kernel_launch(void* const* d_in, const int* in_sizes, int n_in,
                              void* d_out, int out_size, void* d_ws, size_t ws_size,
                              hipStream_t stream)
{
    const float* x_c      = (const float*)d_in[0];
    const float* y_c      = (const float*)d_in[1];
    const float* x_g      = (const float*)d_in[2];
    const float* sigma    = (const float*)d_in[3];
    const float* mu       = (const float*)d_in[4];
    const float* eps1     = (const float*)d_in[5];
    const float* b_u      = (const float*)d_in[6];
    const float* random_w = (const float*)d_in[7];
    const float* conv_w1  = (const float*)d_in[8];
    const float* conv_b1  = (const float*)d_in[9];
    const float* conv_w2  = (const float*)d_in[10];
    const float* conv_b2  = (const float*)d_in[11];
    const float* conv_w3  = (const float*)d_in[12];
    const float* conv_b3  = (const float*)d_in[13];
    const float* bn_gamma = (const float*)d_in[14];
    const float* bn_beta  = (const float*)d_in[15];
    const float* g_w      = (const float*)d_in[16];
    const float* g_b      = (const float*)d_in[17];

    float* outp = (float*)d_out;
    float* wsp  = (float*)d_ws;

    k1_rbf<<<NBB*(NGG/32), 256, 0, stream>>>(x_c, y_c, x_g, sigma, mu, eps1, b_u,
                                             random_w, outp, wsp);
    k2_conv<<<NBB*9*(NGG/256), 256, 0, stream>>>(conv_w1, conv_b1, conv_w2, conv_b2,
                                                 conv_w3, conv_b3, wsp);
    k3_out<<<(NBB*NGG)/4, 256, 0, stream>>>(bn_gamma, bn_beta, g_w, g_b, outp, wsp);
}